// Round 2
// baseline (277.460 us; speedup 1.0000x reference)
//
#include <hip/hip_runtime.h>

#define NB 4
#define LL 8192
#define DD 1024
#define EPSV 1e-4f

#define TILE 32
#define NTILE (LL / TILE)      // 256 tiles per batch
#define NBLK (NB * NTILE)      // 1024 blocks

// ---------------- K1: mask dtype detect + cumsum idx + clipped p ----------------
__global__ __launch_bounds__(1024) void k_prep(const void* __restrict__ mask_raw,
                                               const float* __restrict__ bprob,
                                               int* __restrict__ idx,
                                               float* __restrict__ p_out) {
    const int b = blockIdx.x;
    const int tid = threadIdx.x;
    __shared__ int s_viol;
    __shared__ int s_sums[1024];
    if (tid == 0) s_viol = 0;
    __syncthreads();
    // Detect mask storage: int32 little-endian [0/1,0,0,0] vs uint8.
    {
        unsigned int w = ((const unsigned int*)mask_raw)[tid];
        if ((w & 0xFFFFFF00u) != 0u || (w & 0xFFu) > 1u) atomicOr(&s_viol, 1);
    }
    __syncthreads();
    const bool is_int = (s_viol == 0);

    const int base = b * LL + tid * 8;
    int m[8];
    if (is_int) {
        const int* mi = (const int*)mask_raw;
        #pragma unroll
        for (int k = 0; k < 8; ++k) m[k] = mi[base + k];
    } else {
        const unsigned char* mb = (const unsigned char*)mask_raw;
        #pragma unroll
        for (int k = 0; k < 8; ++k) m[k] = (int)mb[base + k];
    }
    int c[8];
    int s = 0;
    #pragma unroll
    for (int k = 0; k < 8; ++k) { s += m[k]; c[k] = s; }
    s_sums[tid] = s;
    __syncthreads();
    for (int off = 1; off < 1024; off <<= 1) {
        int v = s_sums[tid];
        int add = (tid >= off) ? s_sums[tid - off] : 0;
        __syncthreads();
        s_sums[tid] = v + add;
        __syncthreads();
    }
    const int excl = (tid > 0) ? s_sums[tid - 1] : 0;
    #pragma unroll
    for (int k = 0; k < 8; ++k) idx[base + k] = excl + c[k] - 1;

    #pragma unroll
    for (int k = 0; k < 8; ++k) {
        int l = tid * 8 + k;
        float v = bprob[((size_t)(b * LL + l)) * 2 + 1];
        v = fminf(fmaxf(v, EPSV), 1.0f - EPSV);
        if (l == 0) v = 1.0f;
        p_out[b * LL + l] = v;
    }
}

// ---------------- K2: single-pass scan with decoupled lookback ----------------
__device__ __forceinline__ void gl_lds16(const void* g, void* l) {
    __builtin_amdgcn_global_load_lds(
        (const __attribute__((address_space(1))) void*)g,
        (__attribute__((address_space(3))) void*)l, 16, 0, 0);
}

__global__ __launch_bounds__(1024) void k_main(const float* __restrict__ hid,
                                               const int* __restrict__ idx,
                                               const float* __restrict__ p_ws,
                                               float* __restrict__ Aagg,
                                               float* __restrict__ Bagg,
                                               float* __restrict__ Yinc,
                                               int* __restrict__ flags,
                                               int* __restrict__ ticket,
                                               float* __restrict__ out) {
    __shared__ float s_x[TILE * DD];   // 128 KB slab of contiguous hidden rows
    __shared__ float s_p[TILE];
    __shared__ int   s_i[TILE];
    __shared__ int   s_bc[2];          // [0]=ticket, [1]=flag broadcast

    const int tid = threadIdx.x;
    if (tid == 0) s_bc[0] = atomicAdd(ticket, 1);
    __syncthreads();
    const int tkt = s_bc[0];
    const int b = tkt & (NB - 1);      // round-robin batches so 4 chains advance together
    const int t = tkt >> 2;
    const int f = b * NTILE + t;
    const int l0 = t * TILE;

    if (tid < TILE) {
        s_i[tid] = idx[b * LL + l0 + tid];
        s_p[tid] = p_ws[b * LL + l0 + tid];
    }
    __syncthreads();
    const int r0 = s_i[0];
    const int nrow = s_i[TILE - 1] - r0 + 1;   // contiguous rows, <= TILE

    // contiguous slab copy rows r0..r0+nrow-1 -> LDS (16B units, coalesced)
    {
        const char* src = (const char*)(hid + ((size_t)b * LL + r0) * DD);
        char* dst = (char*)s_x;
        const int n16 = nrow * (DD / 4);
        for (int u = tid; u < n16; u += 1024)
            gl_lds16(src + (size_t)u * 16, dst + (size_t)u * 16);
    }
    __syncthreads();   // drains vmcnt before LDS reads

    // local scan from zero seed -> (cumA, prev) = tile affine aggregate
    float prev = 0.f, cumA = 1.f;
    #pragma unroll
    for (int k = 0; k < TILE; ++k) {
        const int rel = s_i[k] - r0;
        const float x = s_x[rel * DD + tid];
        const float p = s_p[k];
        prev = fmaf(p, x, (1.f - p) * prev);
        cumA *= (1.f - p);
    }

    float carry = 0.f;
    if (t == 0) {
        Yinc[(size_t)f * DD + tid] = prev;
        __syncthreads();
        if (tid == 0) {
            __threadfence();
            __hip_atomic_store(&flags[f], 2, __ATOMIC_RELEASE, __HIP_MEMORY_SCOPE_AGENT);
        }
    } else {
        Bagg[(size_t)f * DD + tid] = prev;
        __syncthreads();
        if (tid == 0) {
            __threadfence();
            __hip_atomic_store(&flags[f], 1, __ATOMIC_RELEASE, __HIP_MEMORY_SCOPE_AGENT);
        }
        // decoupled lookback over predecessors
        float s = 1.f;
        int j = f - 1;
        for (;;) {
            if (tid == 0) {
                int fl;
                do {
                    fl = __hip_atomic_load(&flags[j], __ATOMIC_ACQUIRE, __HIP_MEMORY_SCOPE_AGENT);
                } while (fl == 0);
                s_bc[1] = fl;
            }
            __syncthreads();
            const int fl = s_bc[1];
            __syncthreads();
            if (fl == 2) {
                carry = fmaf(s, Yinc[(size_t)j * DD + tid], carry);
                break;
            }
            carry = fmaf(s, Bagg[(size_t)j * DD + tid], carry);
            s *= Aagg[j];
            --j;
        }
        // publish inclusive prefix
        Yinc[(size_t)f * DD + tid] = fmaf(cumA, carry, prev);
        __syncthreads();
        if (tid == 0) {
            __threadfence();
            __hip_atomic_store(&flags[f], 2, __ATOMIC_RELEASE, __HIP_MEMORY_SCOPE_AGENT);
        }
    }
    if (tid == 0) Aagg[f] = cumA;      // note: written before flag=1? -> move up
    // (Aagg must be visible with flag==1; see ordering fix below)

    // final scan seeded with carry, stream to out
    float y = carry;
    float* ob = out + ((size_t)b * LL + l0) * DD + tid;
    #pragma unroll
    for (int k = 0; k < TILE; ++k) {
        const int rel = s_i[k] - r0;
        const float x = s_x[rel * DD + tid];
        const float p = s_p[k];
        y = fmaf(p, x, (1.f - p) * y);
        ob[(size_t)k * DD] = y;
    }
}

// Fix for Aagg ordering: publish Aagg before the release store of flag=1.
// (k_main above writes Aagg too late; corrected kernel below is the one used.)
__global__ __launch_bounds__(1024) void k_main2(const float* __restrict__ hid,
                                                const int* __restrict__ idx,
                                                const float* __restrict__ p_ws,
                                                float* __restrict__ Aagg,
                                                float* __restrict__ Bagg,
                                                float* __restrict__ Yinc,
                                                int* __restrict__ flags,
                                                int* __restrict__ ticket,
                                                float* __restrict__ out) {
    __shared__ float s_x[TILE * DD];
    __shared__ float s_p[TILE];
    __shared__ int   s_i[TILE];
    __shared__ int   s_bc[2];

    const int tid = threadIdx.x;
    if (tid == 0) s_bc[0] = atomicAdd(ticket, 1);
    __syncthreads();
    const int tkt = s_bc[0];
    const int b = tkt & (NB - 1);
    const int t = tkt >> 2;
    const int f = b * NTILE + t;
    const int l0 = t * TILE;

    if (tid < TILE) {
        s_i[tid] = idx[b * LL + l0 + tid];
        s_p[tid] = p_ws[b * LL + l0 + tid];
    }
    __syncthreads();
    const int r0 = s_i[0];
    const int nrow = s_i[TILE - 1] - r0 + 1;

    {
        const char* src = (const char*)(hid + ((size_t)b * LL + r0) * DD);
        char* dst = (char*)s_x;
        const int n16 = nrow * (DD / 4);
        for (int u = tid; u < n16; u += 1024)
            gl_lds16(src + (size_t)u * 16, dst + (size_t)u * 16);
    }
    __syncthreads();

    float prev = 0.f, cumA = 1.f;
    #pragma unroll
    for (int k = 0; k < TILE; ++k) {
        const int rel = s_i[k] - r0;
        const float x = s_x[rel * DD + tid];
        const float p = s_p[k];
        prev = fmaf(p, x, (1.f - p) * prev);
        cumA *= (1.f - p);
    }

    float carry = 0.f;
    if (t == 0) {
        Yinc[(size_t)f * DD + tid] = prev;
        __syncthreads();
        if (tid == 0) {
            __threadfence();
            __hip_atomic_store(&flags[f], 2, __ATOMIC_RELEASE, __HIP_MEMORY_SCOPE_AGENT);
        }
    } else {
        Bagg[(size_t)f * DD + tid] = prev;
        if (tid == 0) Aagg[f] = cumA;          // visible before flag=1
        __syncthreads();
        if (tid == 0) {
            __threadfence();
            __hip_atomic_store(&flags[f], 1, __ATOMIC_RELEASE, __HIP_MEMORY_SCOPE_AGENT);
        }
        float s = 1.f;
        int j = f - 1;
        for (;;) {
            if (tid == 0) {
                int fl;
                do {
                    fl = __hip_atomic_load(&flags[j], __ATOMIC_ACQUIRE, __HIP_MEMORY_SCOPE_AGENT);
                } while (fl == 0);
                s_bc[1] = fl;
            }
            __syncthreads();
            const int fl = s_bc[1];
            __syncthreads();
            if (fl == 2) {
                carry = fmaf(s, Yinc[(size_t)j * DD + tid], carry);
                break;
            }
            carry = fmaf(s, Bagg[(size_t)j * DD + tid], carry);
            s *= Aagg[j];
            --j;
        }
        Yinc[(size_t)f * DD + tid] = fmaf(cumA, carry, prev);
        __syncthreads();
        if (tid == 0) {
            __threadfence();
            __hip_atomic_store(&flags[f], 2, __ATOMIC_RELEASE, __HIP_MEMORY_SCOPE_AGENT);
        }
    }

    float y = carry;
    float* ob = out + ((size_t)b * LL + l0) * DD + tid;
    #pragma unroll
    for (int k = 0; k < TILE; ++k) {
        const int rel = s_i[k] - r0;
        const float x = s_x[rel * DD + tid];
        const float p = s_p[k];
        y = fmaf(p, x, (1.f - p) * y);
        ob[(size_t)k * DD] = y;
    }
}

extern "C" void kernel_launch(void* const* d_in, const int* in_sizes, int n_in,
                              void* d_out, int out_size, void* d_ws, size_t ws_size,
                              hipStream_t stream) {
    const float* hid   = (const float*)d_in[0];
    const void*  mask  = d_in[1];
    const float* bprob = (const float*)d_in[2];
    float* out = (float*)d_out;

    char* ws = (char*)d_ws;
    int*   idx    = (int*)(ws);                       // 128 KB
    float* p_ws   = (float*)(ws + 131072);            // 128 KB
    float* Aagg   = (float*)(ws + 262144);            // 4 KB
    int*   flags  = (int*)(ws + 266240);              // 4 KB
    int*   ticket = (int*)(ws + 270336);              // 4 KB (padded)
    float* Bagg   = (float*)(ws + 274432);            // 4 MB
    float* Yinc   = (float*)(ws + 274432 + 4194304);  // 4 MB

    // reset flags + ticket (harness does not re-poison between replays)
    hipMemsetAsync(ws + 266240, 0, 8192, stream);
    k_prep<<<NB, 1024, 0, stream>>>(mask, bprob, idx, p_ws);
    k_main2<<<NBLK, 1024, 0, stream>>>(hid, idx, p_ws, Aagg, Bagg, Yinc, flags, ticket, out);
}

// Round 3
// 61.487 us; speedup vs baseline: 4.5125x; 4.5125x over previous
//
#include <hip/hip_runtime.h>

#define NB 4
#define LL 8192
#define DD 1024
#define CHUNK 64
#define NT (LL / CHUNK)   // 128 tiles per batch
#define EPSV 1e-4f

// ---------------- K1: mask dtype detect + cumsum idx + clipped p ----------------
// Wave-shuffle scan: 6 shfl_up steps per wave + 16-wave combine (2 barriers total).
__global__ __launch_bounds__(1024) void k_prep(const void* __restrict__ mask_raw,
                                               const float* __restrict__ bprob,
                                               int* __restrict__ idx,
                                               float* __restrict__ p_out) {
    const int b = blockIdx.x;
    const int tid = threadIdx.x;
    const int lane = tid & 63, wv = tid >> 6;   // 16 waves
    __shared__ int s_viol;
    __shared__ int s_wsum[16];
    if (tid == 0) s_viol = 0;
    __syncthreads();
    // Detect mask storage: int32 little-endian [0/1,0,0,0] vs uint8 (check 4 KB).
    {
        unsigned int w = ((const unsigned int*)mask_raw)[tid];
        if ((w & 0xFFFFFF00u) != 0u || (w & 0xFFu) > 1u) atomicOr(&s_viol, 1);
    }
    __syncthreads();
    const bool is_int = (s_viol == 0);

    const int base = b * LL + tid * 8;
    int m[8];
    if (is_int) {
        const int* mi = (const int*)mask_raw;
        #pragma unroll
        for (int k = 0; k < 8; ++k) m[k] = mi[base + k];
    } else {
        const unsigned char* mb = (const unsigned char*)mask_raw;
        #pragma unroll
        for (int k = 0; k < 8; ++k) m[k] = (int)mb[base + k];
    }
    int c[8];
    int s = 0;
    #pragma unroll
    for (int k = 0; k < 8; ++k) { s += m[k]; c[k] = s; }

    // wave-level inclusive scan of per-thread sums
    int v = s;
    #pragma unroll
    for (int off = 1; off < 64; off <<= 1) {
        int u = __shfl_up(v, off, 64);
        if (lane >= off) v += u;
    }
    if (lane == 63) s_wsum[wv] = v;
    __syncthreads();
    if (wv == 0) {
        int w = (lane < 16) ? s_wsum[lane] : 0;
        #pragma unroll
        for (int off = 1; off < 16; off <<= 1) {
            int u = __shfl_up(w, off, 64);
            if (lane >= off) w += u;
        }
        if (lane < 16) s_wsum[lane] = w;
    }
    __syncthreads();
    const int excl = ((wv > 0) ? s_wsum[wv - 1] : 0) + (v - s);
    #pragma unroll
    for (int k = 0; k < 8; ++k) idx[base + k] = excl + c[k] - 1;

    // clipped p (vectorized float2 read of (B,L,2), take .y)
    const float2* bp2 = (const float2*)bprob + (size_t)b * LL + tid * 8;
    #pragma unroll
    for (int k = 0; k < 8; ++k) {
        int l = tid * 8 + k;
        float pv = bp2[k].y;
        pv = fminf(fmaxf(pv, EPSV), 1.0f - EPSV);
        if (l == 0) pv = 1.0f;
        p_out[b * LL + l] = pv;
    }
}

// ---------------- K2: per-tile affine aggregate (A = prod a, Bvec = local scan end) ----
__global__ __launch_bounds__(1024) void k_tile_agg(const float* __restrict__ hid,
                                                   const int* __restrict__ idx,
                                                   const float* __restrict__ p_ws,
                                                   float* __restrict__ A,
                                                   float* __restrict__ Bvec) {
    const int blk = blockIdx.x;            // b*NT + tile
    const int b = blk / NT, tile = blk % NT;
    const int d = threadIdx.x;
    __shared__ int s_idx[CHUNK];
    __shared__ float s_p[CHUNK];
    const int l0 = tile * CHUNK;
    if (d < CHUNK) {
        s_idx[d] = idx[b * LL + l0 + d];
        s_p[d]  = p_ws[b * LL + l0 + d];
    }
    __syncthreads();
    float prev = 0.f, cumA = 1.f;
    const float* hb = hid + (size_t)b * LL * DD + d;
    #pragma unroll 4
    for (int t = 0; t < CHUNK; ++t) {
        float p = s_p[t];
        float x = hb[(size_t)s_idx[t] * DD];
        prev = fmaf(p, x, (1.f - p) * prev);
        cumA *= (1.f - p);
    }
    Bvec[(size_t)blk * DD + d] = prev;
    if (d == 0) A[blk] = cumA;
}

// ---------------- K3: block-parallel affine scan over tiles -> exclusive carry ------
// One block = one batch x 8 d-channels; threads = 128 tiles x 8 d; 7 LDS scan steps.
__global__ __launch_bounds__(1024) void k_carry(const float* __restrict__ A,
                                                const float* __restrict__ Bvec,
                                                float* __restrict__ carry) {
    const int bi = blockIdx.x;                 // NB * (DD/8) = 512 blocks
    const int b = bi / (DD / 8);
    const int ds0 = (bi % (DD / 8)) * 8;
    const int tid = threadIdx.x;               // tile = tid>>3, dl = tid&7
    const int tile = tid >> 3;
    const int d = ds0 + (tid & 7);
    __shared__ float sa[1024], sb[1024];

    sa[tid] = A[b * NT + tile];
    sb[tid] = Bvec[(size_t)(b * NT + tile) * DD + d];
    __syncthreads();
    #pragma unroll
    for (int off = 8; off < 1024; off <<= 1) {     // off in tid units = tile_off*8
        float pa = 1.f, pb = 0.f;
        const bool has = (tid >= off);
        if (has) { pa = sa[tid - off]; pb = sb[tid - off]; }
        __syncthreads();
        if (has) {
            float ca = sa[tid], cb = sb[tid];
            sa[tid] = pa * ca;                     // (a_early*a_late,
            sb[tid] = fmaf(ca, pb, cb);            //  a_late*b_early + b_late)
        }
        __syncthreads();
    }
    // exclusive: carry[tile] = inclusive_b[tile-1] (initial state y=0 so only b matters)
    const float ex = (tile == 0) ? 0.f : sb[tid - 8];
    carry[(size_t)(b * NT + tile) * DD + d] = ex;
}

// ---------------- K4: final scan seeded with carry, write out -----------------------
__global__ __launch_bounds__(1024) void k_final(const float* __restrict__ hid,
                                                const int* __restrict__ idx,
                                                const float* __restrict__ p_ws,
                                                const float* __restrict__ carry,
                                                float* __restrict__ out) {
    const int blk = blockIdx.x;
    const int b = blk / NT, tile = blk % NT;
    const int d = threadIdx.x;
    __shared__ int s_idx[CHUNK];
    __shared__ float s_p[CHUNK];
    const int l0 = tile * CHUNK;
    if (d < CHUNK) {
        s_idx[d] = idx[b * LL + l0 + d];
        s_p[d]  = p_ws[b * LL + l0 + d];
    }
    __syncthreads();
    float prev = carry[(size_t)blk * DD + d];
    const float* hb = hid + (size_t)b * LL * DD + d;
    float* ob = out + ((size_t)b * LL + l0) * DD + d;
    #pragma unroll 4
    for (int t = 0; t < CHUNK; ++t) {
        float p = s_p[t];
        float x = hb[(size_t)s_idx[t] * DD];
        prev = fmaf(p, x, (1.f - p) * prev);
        ob[(size_t)t * DD] = prev;
    }
}

extern "C" void kernel_launch(void* const* d_in, const int* in_sizes, int n_in,
                              void* d_out, int out_size, void* d_ws, size_t ws_size,
                              hipStream_t stream) {
    const float* hid   = (const float*)d_in[0];
    const void*  mask  = d_in[1];
    const float* bprob = (const float*)d_in[2];
    float* out = (float*)d_out;

    char* ws = (char*)d_ws;
    int*   idx   = (int*)(ws);                                   // 128 KB
    float* p_ws  = (float*)(ws + 131072);                        // 128 KB
    float* A     = (float*)(ws + 262144);                        //   2 KB
    float* Bvec  = (float*)(ws + 264192);                        //   2 MB
    float* carry = (float*)(ws + 264192 + 2097152);              //   2 MB

    k_prep<<<NB, 1024, 0, stream>>>(mask, bprob, idx, p_ws);
    k_tile_agg<<<NB * NT, 1024, 0, stream>>>(hid, idx, p_ws, A, Bvec);
    k_carry<<<NB * (DD / 8), 1024, 0, stream>>>(A, Bvec, carry);
    k_final<<<NB * NT, 1024, 0, stream>>>(hid, idx, p_ws, carry, out);
}